// Round 7
// baseline (1577.087 us; speedup 1.0000x reference)
//
#include <hip/hip_runtime.h>
#include <hip/hip_cooperative_groups.h>

namespace cg = cooperative_groups;

#define N_USERS  4096
#define N_NODES  12288
#define N_EDGES  393216
#define D        256
#define SLOPE    0.2f
#define PAD      128   // max node degree ~57 (Poisson(32) over 12288 nodes)
#define SENT     0x7FFFFFFF
#define N_TILES  768   // (12288/64) row-tiles x 4 col-tiles

static __device__ __forceinline__ ushort f2bf_rtne(float f) {
    unsigned int u = __float_as_uint(f);
    u += 0x7FFFu + ((u >> 16) & 1u);
    return (ushort)(u >> 16);
}

// bitonic compare-exchange across lanes (stride ss < 64), element position pp
#define CE_SHFL(v, pp, kk, ss)                                   \
    {                                                            \
        int ok = __shfl_xor(v.x, ss, 64);                        \
        int ov = __shfl_xor(v.y, ss, 64);                        \
        bool lower = ((lane & (ss)) == 0);                       \
        bool up    = (((pp) & (kk)) == 0);                       \
        bool keep  = ((v.x < ok) == (lower == up));              \
        if (!keep) { v.x = ok; v.y = ov; }                       \
    }

#define GATHER4(ACC, W0, RX, RY)                                        \
    ACC.x += (W0) * __int_as_float((int)((RX) << 16));                  \
    ACC.y += (W0) * __int_as_float((int)((RX) & 0xFFFF0000u));          \
    ACC.z += (W0) * __int_as_float((int)((RY) << 16));                  \
    ACC.w += (W0) * __int_as_float((int)((RY) & 0xFFFF0000u));

__global__ __launch_bounds__(256, 2) void k_fused(
        const float* __restrict__ wp,   const float* __restrict__ wn,
        const float* __restrict__ valp, const float* __restrict__ valn,
        const int* __restrict__ src,    const int* __restrict__ dst,
        const int* __restrict__ tix,    const float* __restrict__ T,
        const float* __restrict__ user, const float* __restrict__ item,
        const float* __restrict__ layW,
        int* __restrict__ counts, int2* __restrict__ ell,
        float* __restrict__ Bm, float* __restrict__ h,
        ushort* __restrict__ hwb, float* __restrict__ out) {
    cg::grid_group grid = cg::this_grid();
    __shared__ float As[32 * 64];
    __shared__ float Bs[32 * 64];

    const int tid     = threadIdx.x;
    const int nBlocks = gridDim.x;
    const int gThreads = nBlocks * 256;
    const int gWaves   = nBlocks * 4;
    const int gtid  = blockIdx.x * 256 + tid;
    const int lane  = tid & 63;
    const int gwave = blockIdx.x * 4 + (tid >> 6);

    // ---------- phase 0: zero per-dst counters ----------
    for (int i = gtid; i < N_NODES; i += gThreads) counts[i] = 0;
    grid.sync();

    // ---------- phase 1: edge scatter into ELL ----------
    for (int e = gtid; e < N_EDGES; e += gThreads) {
        int s = src[e], d0 = dst[e];
        size_t mi = (size_t)s * N_NODES + (size_t)d0;
        float w = valp[e] * wp[mi] - valn[e] * wn[mi];
        int slot = atomicAdd(&counts[d0], 1);
        ell[(size_t)d0 * PAD + slot] = make_int2((s << 16) | (tix[e] << 7) | slot,
                                                 __float_as_int(w));
    }
    grid.sync();

    // ---------- phase 2: per-node row sort + time term + init ----------
    for (int n = gwave; n < N_NODES; n += gWaves) {
        int m = counts[n];
        int2* row = &ell[(size_t)n * PAD];
        int2 a = row[lane];
        int2 b = row[lane + 64];
        if (lane >= m)      a = make_int2(SENT, 0);
        if (lane + 64 >= m) b = make_int2(SENT, 0);
#pragma unroll
        for (int k = 2; k <= 128; k <<= 1) {
            if (k == 128) {
                if (a.x > b.x) { int2 t = a; a = b; b = t; }
            }
#pragma unroll
            for (int s = (k == 128 ? 32 : (k >> 1)); s >= 1; s >>= 1) {
                CE_SHFL(a, lane, k, s);
                CE_SHFL(b, lane + 64, k, s);
            }
        }
        row[lane] = a;
        row[lane + 64] = b;

        const float4* T4 = (const float4*)T;
        float4 acc = make_float4(0.f, 0.f, 0.f, 0.f);
        for (int half = 0; half < 2; ++half) {
            int base = half * 64;
            if (m <= base) break;
            int mm = min(64, m - base);
            int2 v = half ? b : a;
            int   te = (v.x >> 7) & 0x1FF;
            float we = __int_as_float(v.y);
            int j = 0;
            for (; j + 4 <= mm; j += 4) {
                int   t0 = __shfl(te, j),     t1 = __shfl(te, j + 1),
                      t2 = __shfl(te, j + 2), t3 = __shfl(te, j + 3);
                float w0 = __shfl(we, j),     w1 = __shfl(we, j + 1),
                      w2 = __shfl(we, j + 2), w3 = __shfl(we, j + 3);
                float4 r0 = T4[t0 * 64 + lane];
                float4 r1 = T4[t1 * 64 + lane];
                float4 r2 = T4[t2 * 64 + lane];
                float4 r3 = T4[t3 * 64 + lane];
                acc.x += w0 * r0.x + w1 * r1.x + w2 * r2.x + w3 * r3.x;
                acc.y += w0 * r0.y + w1 * r1.y + w2 * r2.y + w3 * r3.y;
                acc.z += w0 * r0.z + w1 * r1.z + w2 * r2.z + w3 * r3.z;
                acc.w += w0 * r0.w + w1 * r1.w + w2 * r2.w + w3 * r3.w;
            }
            for (; j < mm; ++j) {
                int t0 = __shfl(te, j); float w0 = __shfl(we, j);
                float4 r0 = T4[t0 * 64 + lane];
                acc.x += w0 * r0.x; acc.y += w0 * r0.y;
                acc.z += w0 * r0.z; acc.w += w0 * r0.w;
            }
        }
        ((float4*)Bm)[n * 64 + lane] = acc;

        const float4* s4 = (n < N_USERS) ? ((const float4*)user) + (size_t)n * 64
                                         : ((const float4*)item) + (size_t)(n - N_USERS) * 64;
        float4 u = s4[lane];
        ((float4*)h)[n * 64 + lane] = u;
        ((float4*)out)[(size_t)n * 256 + lane] = u;
    }
    grid.sync();

    // ---------- 3 layers ----------
    for (int l = 0; l < 3; ++l) {
        // ---- gemm phase: grid-stride over 768 64x64 tiles ----
        {
            const float* W = layW + (size_t)l * 256 * 256;
            int tx = tid & 15, ty = tid >> 4;
            for (int tile = blockIdx.x; tile < N_TILES; tile += nBlocks) {
                int row0 = (tile >> 2) * 64, c0 = (tile & 3) * 64;
                float acc[4][4] = {};
                for (int k0 = 0; k0 < 256; k0 += 32) {
                    {   // stage A (64 rows x 32 k), transposed into LDS
                        int r  = tid >> 2;
                        int kq = (tid & 3) * 8;
                        const float* s = &h[(row0 + r) * 256 + k0 + kq];
                        float4 a0 = *(const float4*)s;
                        float4 a1 = *(const float4*)(s + 4);
                        As[(kq + 0) * 64 + r] = a0.x; As[(kq + 1) * 64 + r] = a0.y;
                        As[(kq + 2) * 64 + r] = a0.z; As[(kq + 3) * 64 + r] = a0.w;
                        As[(kq + 4) * 64 + r] = a1.x; As[(kq + 5) * 64 + r] = a1.y;
                        As[(kq + 6) * 64 + r] = a1.z; As[(kq + 7) * 64 + r] = a1.w;
                    }
                    {   // stage B (32 k x 64 cols)
                        int kb = tid >> 3;
                        int c8 = (tid & 7) * 8;
                        const float* ws = &W[(k0 + kb) * 256 + c0 + c8];
                        float4 b0 = *(const float4*)ws;
                        float4 b1 = *(const float4*)(ws + 4);
                        float* bd = &Bs[kb * 64 + c8];
                        bd[0] = b0.x; bd[1] = b0.y; bd[2] = b0.z; bd[3] = b0.w;
                        bd[4] = b1.x; bd[5] = b1.y; bd[6] = b1.z; bd[7] = b1.w;
                    }
                    __syncthreads();
#pragma unroll
                    for (int kk = 0; kk < 32; ++kk) {
                        float4 a = *(const float4*)&As[kk * 64 + ty * 4];
                        float4 b = *(const float4*)&Bs[kk * 64 + tx * 4];
                        acc[0][0] += a.x * b.x; acc[0][1] += a.x * b.y; acc[0][2] += a.x * b.z; acc[0][3] += a.x * b.w;
                        acc[1][0] += a.y * b.x; acc[1][1] += a.y * b.y; acc[1][2] += a.y * b.z; acc[1][3] += a.y * b.w;
                        acc[2][0] += a.z * b.x; acc[2][1] += a.z * b.y; acc[2][2] += a.z * b.z; acc[2][3] += a.z * b.w;
                        acc[3][0] += a.w * b.x; acc[3][1] += a.w * b.y; acc[3][2] += a.w * b.z; acc[3][3] += a.w * b.w;
                    }
                    __syncthreads();
                }
#pragma unroll
                for (int i = 0; i < 4; ++i) {
                    ushort4 o;
                    o.x = f2bf_rtne(acc[i][0]); o.y = f2bf_rtne(acc[i][1]);
                    o.z = f2bf_rtne(acc[i][2]); o.w = f2bf_rtne(acc[i][3]);
                    *(ushort4*)&hwb[(size_t)(row0 + ty * 4 + i) * 256 + c0 + tx * 4] = o;
                }
            }
        }
        grid.sync();

        // ---- agg phase: one wave per node (grid-stride) ----
        for (int n = gwave; n < N_NODES; n += gWaves) {
            int m = counts[n];
            const uint2* hw2 = (const uint2*)hwb;
            const int2* row = &ell[(size_t)n * PAD];
            float4 acc = ((const float4*)Bm)[n * 64 + lane];
            for (int base = 0; base < m; base += 64) {
                int idx = base + lane;
                int2 md = (idx < m) ? row[idx] : make_int2(SENT, 0);
                int   se = md.x >> 16;
                float we = __int_as_float(md.y);
                int mm = min(64, m - base);
                int j = 0;
                for (; j + 4 <= mm; j += 4) {
                    int   s0 = __shfl(se, j),     s1 = __shfl(se, j + 1),
                          s2 = __shfl(se, j + 2), s3 = __shfl(se, j + 3);
                    float w0 = __shfl(we, j),     w1 = __shfl(we, j + 1),
                          w2 = __shfl(we, j + 2), w3 = __shfl(we, j + 3);
                    uint2 r0 = hw2[s0 * 64 + lane];
                    uint2 r1 = hw2[s1 * 64 + lane];
                    uint2 r2 = hw2[s2 * 64 + lane];
                    uint2 r3 = hw2[s3 * 64 + lane];
                    GATHER4(acc, w0, r0.x, r0.y);
                    GATHER4(acc, w1, r1.x, r1.y);
                    GATHER4(acc, w2, r2.x, r2.y);
                    GATHER4(acc, w3, r3.x, r3.y);
                }
                for (; j < mm; ++j) {
                    int s0 = __shfl(se, j); float w0 = __shfl(we, j);
                    uint2 r0 = hw2[s0 * 64 + lane];
                    GATHER4(acc, w0, r0.x, r0.y);
                }
            }
            float4 v;
            v.x = (acc.x >= 0.f) ? acc.x : SLOPE * acc.x;
            v.y = (acc.y >= 0.f) ? acc.y : SLOPE * acc.y;
            v.z = (acc.z >= 0.f) ? acc.z : SLOPE * acc.z;
            v.w = (acc.w >= 0.f) ? acc.w : SLOPE * acc.w;
            ((float4*)h)[n * 64 + lane] = v;
            float sq = v.x * v.x + v.y * v.y + v.z * v.z + v.w * v.w;
#pragma unroll
            for (int off = 1; off < 64; off <<= 1) sq += __shfl_xor(sq, off, 64);
            float scale = 1.0f / fmaxf(sqrtf(sq), 1e-12f);
            float4 o = make_float4(v.x * scale, v.y * scale, v.z * scale, v.w * scale);
            ((float4*)out)[(size_t)n * 256 + (size_t)(l + 1) * 64 + lane] = o;
        }
        if (l < 2) grid.sync();
    }
}

extern "C" void kernel_launch(void* const* d_in, const int* in_sizes, int n_in,
                              void* d_out, int out_size, void* d_ws, size_t ws_size,
                              hipStream_t stream) {
    const float* user  = (const float*)d_in[0];
    const float* item  = (const float*)d_in[1];
    const float* wp    = (const float*)d_in[2];
    const float* wn    = (const float*)d_in[3];
    const float* layW  = (const float*)d_in[4];
    const float* ttab  = (const float*)d_in[5];
    const float* valp  = (const float*)d_in[6];
    const float* valn  = (const float*)d_in[7];
    const int*   src   = (const int*)d_in[8];
    const int*   dst   = (const int*)d_in[9];
    const int*   tix   = (const int*)d_in[10];
    float* out = (float*)d_out;

    char* p = (char*)d_ws;
    auto carve = [&](size_t bytes) {
        char* r = p;
        p += (bytes + 255) & ~(size_t)255;
        return r;
    };
    int*    counts = (int*)   carve((size_t)N_NODES * 4);
    int2*   ell    = (int2*)  carve((size_t)N_NODES * PAD * 8);
    float*  Bm     = (float*) carve((size_t)N_NODES * D * 4);
    float*  h      = (float*) carve((size_t)N_NODES * D * 4);
    ushort* hwb    = (ushort*)carve((size_t)N_NODES * D * 2);

    // Occupancy-clamped cooperative grid: never exceed resident capacity.
    int maxB = 0;
    hipOccupancyMaxActiveBlocksPerMultiprocessor(&maxB, k_fused, 256, 0);
    int blocks = maxB * 256;          // 256 CUs on MI355X
    if (blocks > 384) blocks = 384;   // target: 1.5 blocks/CU, 768 gemm tiles = 2/block
    if (blocks < 64)  blocks = 64;    // paranoia floor (grid-stride handles any size)

    void* args[] = {
        (void*)&wp, (void*)&wn, (void*)&valp, (void*)&valn,
        (void*)&src, (void*)&dst, (void*)&tix, (void*)&ttab,
        (void*)&user, (void*)&item, (void*)&layW,
        (void*)&counts, (void*)&ell, (void*)&Bm, (void*)&h,
        (void*)&hwb, (void*)&out
    };
    hipLaunchCooperativeKernel((const void*)k_fused, dim3(blocks), dim3(256),
                               args, 0, stream);
}

// Round 8
// 1073.615 us; speedup vs baseline: 1.4689x; 1.4689x over previous
//
#include <hip/hip_runtime.h>

#define N_USERS  4096
#define N_NODES  12288
#define N_EDGES  393216
#define D        256
#define SLOPE    0.2f
#define PAD      128   // max node degree ~57 (Poisson(32) over 12288 nodes)
#define SENT     0x7FFFFFFF

typedef __attribute__((ext_vector_type(8))) short short8;   // 8 x bf16 (4 VGPRs)
typedef __attribute__((ext_vector_type(4))) float f32x4;    // MFMA accumulator

static __device__ __forceinline__ ushort f2bf_rtne(float f) {
    unsigned int u = __float_as_uint(f);
    u += 0x7FFFu + ((u >> 16) & 1u);
    return (ushort)(u >> 16);
}

// prep: zero per-dst counters AND build Wt[l][n][k] = bf16(W[l][k][n])
// grid: 768 x 256 = 196608 threads = 3*65536 Wt elements exactly
__global__ void k_prep(const float* __restrict__ W, ushort* __restrict__ Wt,
                       int* __restrict__ counts) {
    int idx = blockIdx.x * 256 + threadIdx.x;
    if (idx < N_NODES) counts[idx] = 0;
    int l = idx >> 16;
    int r = idx & 65535;
    int n = r >> 8, k = r & 255;
    Wt[(size_t)l * 65536 + n * 256 + k] = f2bf_rtne(W[(size_t)l * 65536 + k * 256 + n]);
}

// Edge weight from wp/wn random gather (nontemporal: zero reuse);
// one 8B packed write into ELL[dst][slot]. key: src<<16 | t<<7 | slot (unique)
__global__ void k_scatter_ell(const float* __restrict__ wp, const float* __restrict__ wn,
                              const float* __restrict__ valp, const float* __restrict__ valn,
                              const int* __restrict__ src, const int* __restrict__ dst,
                              const int* __restrict__ tix,
                              int* __restrict__ counts, int2* __restrict__ ell) {
    int e = blockIdx.x * blockDim.x + threadIdx.x;
    if (e >= N_EDGES) return;
    int s = src[e], d0 = dst[e];
    size_t mi = (size_t)s * N_NODES + (size_t)d0;
    float a = __builtin_nontemporal_load(wp + mi);
    float b = __builtin_nontemporal_load(wn + mi);
    float w = valp[e] * a - valn[e] * b;
    int slot = atomicAdd(&counts[d0], 1);
    ell[(size_t)d0 * PAD + slot] = make_int2((s << 16) | (tix[e] << 7) | slot,
                                             __float_as_int(w));
}

// bitonic compare-exchange across lanes (stride ss < 64), element position pp
#define CE_SHFL(v, pp, kk, ss)                                   \
    {                                                            \
        int ok = __shfl_xor(v.x, ss, 64);                        \
        int ov = __shfl_xor(v.y, ss, 64);                        \
        bool lower = ((lane & (ss)) == 0);                       \
        bool up    = (((pp) & (kk)) == 0);                       \
        bool keep  = ((v.x < ok) == (lower == up));              \
        if (!keep) { v.x = ok; v.y = ov; }                       \
    }

// Per node (one wave): sort ELL row by src; Bm = sum w_e*T[t_e]; init h(bf16)+out
__global__ __launch_bounds__(256) void k_build_B_init(
        const int* __restrict__ counts, int2* __restrict__ ell,
        const float* __restrict__ T,
        const float* __restrict__ user, const float* __restrict__ item,
        float* __restrict__ Bm, ushort* __restrict__ hb, float* __restrict__ out) {
    int wv = threadIdx.x >> 6, lane = threadIdx.x & 63;
    int n = blockIdx.x * 4 + wv;
    int m = counts[n];
    int2* row = &ell[(size_t)n * PAD];

    int2 a = row[lane];
    int2 b = row[lane + 64];
    if (lane >= m)      a = make_int2(SENT, 0);
    if (lane + 64 >= m) b = make_int2(SENT, 0);
#pragma unroll
    for (int k = 2; k <= 128; k <<= 1) {
        if (k == 128) {
            if (a.x > b.x) { int2 t = a; a = b; b = t; }
        }
#pragma unroll
        for (int s = (k == 128 ? 32 : (k >> 1)); s >= 1; s >>= 1) {
            CE_SHFL(a, lane, k, s);
            CE_SHFL(b, lane + 64, k, s);
        }
    }
    row[lane] = a;
    row[lane + 64] = b;

    const float4* T4 = (const float4*)T;
    float4 acc = make_float4(0.f, 0.f, 0.f, 0.f);
    for (int half = 0; half < 2; ++half) {
        int base = half * 64;
        if (m <= base) break;
        int mm = min(64, m - base);
        int2 v = half ? b : a;
        int   te = (v.x >> 7) & 0x1FF;
        float we = __int_as_float(v.y);
        int j = 0;
        for (; j + 4 <= mm; j += 4) {
            int   t0 = __shfl(te, j),     t1 = __shfl(te, j + 1),
                  t2 = __shfl(te, j + 2), t3 = __shfl(te, j + 3);
            float w0 = __shfl(we, j),     w1 = __shfl(we, j + 1),
                  w2 = __shfl(we, j + 2), w3 = __shfl(we, j + 3);
            float4 r0 = T4[t0 * 64 + lane];
            float4 r1 = T4[t1 * 64 + lane];
            float4 r2 = T4[t2 * 64 + lane];
            float4 r3 = T4[t3 * 64 + lane];
            acc.x += w0 * r0.x + w1 * r1.x + w2 * r2.x + w3 * r3.x;
            acc.y += w0 * r0.y + w1 * r1.y + w2 * r2.y + w3 * r3.y;
            acc.z += w0 * r0.z + w1 * r1.z + w2 * r2.z + w3 * r3.z;
            acc.w += w0 * r0.w + w1 * r1.w + w2 * r2.w + w3 * r3.w;
        }
        for (; j < mm; ++j) {
            int t0 = __shfl(te, j); float w0 = __shfl(we, j);
            float4 r0 = T4[t0 * 64 + lane];
            acc.x += w0 * r0.x; acc.y += w0 * r0.y;
            acc.z += w0 * r0.z; acc.w += w0 * r0.w;
        }
    }
    ((float4*)Bm)[n * 64 + lane] = acc;

    const float4* s4 = (n < N_USERS) ? ((const float4*)user) + (size_t)n * 64
                                     : ((const float4*)item) + (size_t)(n - N_USERS) * 64;
    float4 u = s4[lane];
    ((ushort4*)hb)[n * 64 + lane] = make_ushort4(f2bf_rtne(u.x), f2bf_rtne(u.y),
                                                 f2bf_rtne(u.z), f2bf_rtne(u.w));
    ((float4*)out)[(size_t)n * 256 + lane] = u;
}

// MFMA bf16 GEMM: hwb = bf16( hb @ W )   using Wt[n][k] (B-operand, K-contiguous)
// block = 4 waves; block tile 64 rows x 64 cols; wave tile 16 rows x 64 cols.
// A-frag: lane m=lane&15, k=quad*8+j ; B-frag: n=lane&15, k=quad*8+j ;
// C/D: col=lane&15, row=quad*4+reg   (verified gfx950 layouts)
__global__ __launch_bounds__(256) void k_gemm(const ushort* __restrict__ hb,
                                              const ushort* __restrict__ Wt,
                                              ushort* __restrict__ hwb) {
    int tid = threadIdx.x;
    int wv = tid >> 6, lane = tid & 63;
    int quad = lane >> 4, l16 = lane & 15;
    int row0 = blockIdx.x * 64 + wv * 16;
    int c0 = blockIdx.y * 64;

    const short8* arow = (const short8*)&hb[(size_t)(row0 + l16) * 256];
    const short8* b0p  = (const short8*)&Wt[(size_t)(c0 +  0 + l16) * 256];
    const short8* b1p  = (const short8*)&Wt[(size_t)(c0 + 16 + l16) * 256];
    const short8* b2p  = (const short8*)&Wt[(size_t)(c0 + 32 + l16) * 256];
    const short8* b3p  = (const short8*)&Wt[(size_t)(c0 + 48 + l16) * 256];

    f32x4 acc0 = {0.f, 0.f, 0.f, 0.f}, acc1 = acc0, acc2 = acc0, acc3 = acc0;
#pragma unroll
    for (int k0 = 0; k0 < 32; k0 += 4) {      // short8 index: k = idx*8; quad adds its 8
        short8 av = arow[k0 + quad];
        short8 bv0 = b0p[k0 + quad];
        short8 bv1 = b1p[k0 + quad];
        short8 bv2 = b2p[k0 + quad];
        short8 bv3 = b3p[k0 + quad];
        acc0 = __builtin_amdgcn_mfma_f32_16x16x32_bf16(av, bv0, acc0, 0, 0, 0);
        acc1 = __builtin_amdgcn_mfma_f32_16x16x32_bf16(av, bv1, acc1, 0, 0, 0);
        acc2 = __builtin_amdgcn_mfma_f32_16x16x32_bf16(av, bv2, acc2, 0, 0, 0);
        acc3 = __builtin_amdgcn_mfma_f32_16x16x32_bf16(av, bv3, acc3, 0, 0, 0);
    }
#pragma unroll
    for (int r = 0; r < 4; ++r) {
        size_t rowoff = (size_t)(row0 + quad * 4 + r) * 256 + c0 + l16;
        hwb[rowoff +  0] = f2bf_rtne(acc0[r]);
        hwb[rowoff + 16] = f2bf_rtne(acc1[r]);
        hwb[rowoff + 32] = f2bf_rtne(acc2[r]);
        hwb[rowoff + 48] = f2bf_rtne(acc3[r]);
    }
}

#define GATHER4(ACC, W0, RX, RY)                                        \
    ACC.x += (W0) * __int_as_float((int)((RX) << 16));                  \
    ACC.y += (W0) * __int_as_float((int)((RX) & 0xFFFF0000u));          \
    ACC.z += (W0) * __int_as_float((int)((RY) << 16));                  \
    ACC.w += (W0) * __int_as_float((int)((RY) & 0xFFFF0000u));

// agg[n,:] = Bm[n,:] + sum_slots w * hwb[src,:]  (one wave per node, src-sorted)
// h(bf16) = leaky_relu(agg); out block (layer+1) = normalized f32
__global__ __launch_bounds__(256) void k_agg(
        const int* __restrict__ counts, const int2* __restrict__ ell,
        const ushort* __restrict__ hwb, const float* __restrict__ Bm,
        ushort* __restrict__ hb, float* __restrict__ out, int layer) {
    int wv = threadIdx.x >> 6, lane = threadIdx.x & 63;
    int n = blockIdx.x * 4 + wv;
    int m = counts[n];
    const uint2* hw2 = (const uint2*)hwb;
    const int2* row = &ell[(size_t)n * PAD];
    float4 acc = ((const float4*)Bm)[n * 64 + lane];
    for (int base = 0; base < m; base += 64) {
        int idx = base + lane;
        int2 md = (idx < m) ? row[idx] : make_int2(SENT, 0);
        int   se = md.x >> 16;
        float we = __int_as_float(md.y);
        int mm = min(64, m - base);
        int j = 0;
        for (; j + 4 <= mm; j += 4) {
            int   s0 = __shfl(se, j),     s1 = __shfl(se, j + 1),
                  s2 = __shfl(se, j + 2), s3 = __shfl(se, j + 3);
            float w0 = __shfl(we, j),     w1 = __shfl(we, j + 1),
                  w2 = __shfl(we, j + 2), w3 = __shfl(we, j + 3);
            uint2 r0 = hw2[s0 * 64 + lane];
            uint2 r1 = hw2[s1 * 64 + lane];
            uint2 r2 = hw2[s2 * 64 + lane];
            uint2 r3 = hw2[s3 * 64 + lane];
            GATHER4(acc, w0, r0.x, r0.y);
            GATHER4(acc, w1, r1.x, r1.y);
            GATHER4(acc, w2, r2.x, r2.y);
            GATHER4(acc, w3, r3.x, r3.y);
        }
        for (; j < mm; ++j) {
            int s0 = __shfl(se, j); float w0 = __shfl(we, j);
            uint2 r0 = hw2[s0 * 64 + lane];
            GATHER4(acc, w0, r0.x, r0.y);
        }
    }
    float4 v;
    v.x = (acc.x >= 0.f) ? acc.x : SLOPE * acc.x;
    v.y = (acc.y >= 0.f) ? acc.y : SLOPE * acc.y;
    v.z = (acc.z >= 0.f) ? acc.z : SLOPE * acc.z;
    v.w = (acc.w >= 0.f) ? acc.w : SLOPE * acc.w;
    ((ushort4*)hb)[n * 64 + lane] = make_ushort4(f2bf_rtne(v.x), f2bf_rtne(v.y),
                                                 f2bf_rtne(v.z), f2bf_rtne(v.w));
    float sq = v.x * v.x + v.y * v.y + v.z * v.z + v.w * v.w;
#pragma unroll
    for (int off = 1; off < 64; off <<= 1) sq += __shfl_xor(sq, off, 64);
    float scale = 1.0f / fmaxf(sqrtf(sq), 1e-12f);
    float4 o = make_float4(v.x * scale, v.y * scale, v.z * scale, v.w * scale);
    ((float4*)out)[(size_t)n * 256 + (size_t)(layer + 1) * 64 + lane] = o;
}

extern "C" void kernel_launch(void* const* d_in, const int* in_sizes, int n_in,
                              void* d_out, int out_size, void* d_ws, size_t ws_size,
                              hipStream_t stream) {
    const float* user  = (const float*)d_in[0];
    const float* item  = (const float*)d_in[1];
    const float* wp    = (const float*)d_in[2];
    const float* wn    = (const float*)d_in[3];
    const float* layW  = (const float*)d_in[4];
    const float* ttab  = (const float*)d_in[5];
    const float* valp  = (const float*)d_in[6];
    const float* valn  = (const float*)d_in[7];
    const int*   src   = (const int*)d_in[8];
    const int*   dst   = (const int*)d_in[9];
    const int*   tix   = (const int*)d_in[10];
    float* out = (float*)d_out;

    char* p = (char*)d_ws;
    auto carve = [&](size_t bytes) {
        char* r = p;
        p += (bytes + 255) & ~(size_t)255;
        return r;
    };
    int*    counts = (int*)   carve((size_t)N_NODES * 4);
    int2*   ell    = (int2*)  carve((size_t)N_NODES * PAD * 8);
    float*  Bm     = (float*) carve((size_t)N_NODES * D * 4);
    ushort* hb     = (ushort*)carve((size_t)N_NODES * D * 2);
    ushort* hwb    = (ushort*)carve((size_t)N_NODES * D * 2);
    ushort* Wt     = (ushort*)carve((size_t)3 * 65536 * 2);

    k_prep<<<768, 256, 0, stream>>>(layW, Wt, counts);
    k_scatter_ell<<<N_EDGES / 256, 256, 0, stream>>>(wp, wn, valp, valn, src, dst, tix,
                                                     counts, ell);
    k_build_B_init<<<N_NODES / 4, 256, 0, stream>>>(counts, ell, ttab, user, item,
                                                    Bm, hb, out);
    for (int l = 0; l < 3; ++l) {
        k_gemm<<<dim3(N_NODES / 64, 4), 256, 0, stream>>>(hb, Wt + (size_t)l * 65536, hwb);
        k_agg<<<N_NODES / 4, 256, 0, stream>>>(counts, ell, hwb, Bm, hb, out, l);
    }
}